// Round 6
// baseline (44.190 us; speedup 1.0000x reference)
//
#include <hip/hip_runtime.h>

// 9x9 clipped box-SUM on (8,3,1024,1024) f32 — fused, full-width block,
// barrier-free horizontal pass, ONE __syncthreads per chunk.
//
// Block = 256 threads = 4 waves x 256 cols = exactly W=1024 (no lane waste,
// no horizontal halo fetch; perfect 256B-aligned 1KB row segments per wave).
//
// Vertical: per-thread rolling 9-row window sum over a 16-row chunk, staged
// r[25] + saved V16[16], all static indices (rule #20 — no scratch;
// tripwire: WRITE_SIZE must stay ~97MB).
//
// Horizontal: 9-tap via 8 in-wave shuffles (round-4 scheme). Cross-wave
// boundary V exchanged through a tiny LDS slab written in phase 1, read
// (broadcast) in phase 2 — single barrier between phases, instead of
// round 5's 16 per-row barriers.

constexpr int H = 1024, W = 1024;
constexpr int RAD = 4;
constexpr int CHUNK = 16;
constexpr int NCHUNK = H / CHUNK;           // 64
constexpr int NIMG = 24;                    // 8 * 3
constexpr int NROWS = CHUNK + 2 * RAD + 1;  // 25
constexpr int TPB = 256;                    // 4 waves, one float4/thread

__global__ __launch_bounds__(TPB) void box9_kernel(const float* __restrict__ x,
                                                   float* __restrict__ out) {
    // L0s[w][j]  = wave w, lane 0's V at row j   (right halo for wave w-1)
    // L63s[w+1][j] = wave w, lane 63's V at row j (left halo for wave w+1)
    // L63s[0][*] and L0s[4][*] stay zero = clipped image edges.
    __shared__ float4 L63s[5][CHUNK];
    __shared__ float4 L0s[5][CHUNK];

    const int t    = threadIdx.x;
    const int lane = t & 63;
    const int wv   = t >> 6;                // wave index in block: 0..3
    const int bid  = blockIdx.x;
    const int chunk = bid & (NCHUNK - 1);   // 64 chunks
    const int img   = bid >> 6;

    if (t < CHUNK)               L63s[0][t] = make_float4(0.f, 0.f, 0.f, 0.f);
    else if (t < 2 * CHUNK)      L0s[4][t - CHUNK] = make_float4(0.f, 0.f, 0.f, 0.f);

    const float* xp = x   + (size_t)img * (H * W) + 4 * t;   // col 4t
    float*       op = out + (size_t)img * (H * W) + 4 * t;
    const int h0 = chunk * CHUNK;

    // Stage chunk + vertical halo: 25 independent 16B loads.
    float4 r[NROWS];
#pragma unroll
    for (int j = 0; j < NROWS; ++j) {
        const int row = h0 - RAD + j;
        r[j] = ((unsigned)row < (unsigned)H)
             ? *reinterpret_cast<const float4*>(xp + (size_t)row * W)
             : make_float4(0.f, 0.f, 0.f, 0.f);
    }

    // Phase 1: roll the vertical window, save per-row V, export edge V's.
    float4 V = make_float4(0.f, 0.f, 0.f, 0.f);
#pragma unroll
    for (int j = 0; j < 9; ++j) {
        V.x += r[j].x; V.y += r[j].y; V.z += r[j].z; V.w += r[j].w;
    }

    float4 V16[CHUNK];
#pragma unroll
    for (int j = 0; j < CHUNK; ++j) {
        V16[j] = V;
        if (lane == 0)  L0s[wv][j]      = V;
        if (lane == 63) L63s[wv + 1][j] = V;
        V.x += r[j + 9].x - r[j].x;
        V.y += r[j + 9].y - r[j].y;
        V.z += r[j + 9].z - r[j].z;
        V.w += r[j + 9].w - r[j].w;
    }

    __syncthreads();   // the ONLY barrier in the kernel

    // Phase 2: horizontal 9-tap per row, barrier-free.
#pragma unroll
    for (int j = 0; j < CHUNK; ++j) {
        const float4 Vj = V16[j];
        float4 VL, VR;
        VL.x = __shfl(Vj.x, lane - 1);
        VL.y = __shfl(Vj.y, lane - 1);
        VL.z = __shfl(Vj.z, lane - 1);
        VL.w = __shfl(Vj.w, lane - 1);
        VR.x = __shfl(Vj.x, lane + 1);
        VR.y = __shfl(Vj.y, lane + 1);
        VR.z = __shfl(Vj.z, lane + 1);
        VR.w = __shfl(Vj.w, lane + 1);
        if (lane == 0)  VL = L63s[wv][j];       // broadcast LDS read
        if (lane == 63) VR = L0s[wv + 1][j];    // broadcast LDS read

        const float T   = Vj.x + Vj.y + Vj.z + Vj.w;
        const float ls3 = VL.w;
        const float ls2 = ls3 + VL.z;
        const float ls1 = ls2 + VL.y;
        const float lT  = ls1 + VL.x;
        const float rp0 = VR.x;
        const float rp1 = rp0 + VR.y;
        const float rp2 = rp1 + VR.z;
        const float rT  = rp2 + VR.w;

        float4 o;
        o.x = lT  + T + rp0;   // col 4t   : window 4t-4 .. 4t+4
        o.y = ls1 + T + rp1;   // col 4t+1
        o.z = ls2 + T + rp2;   // col 4t+2
        o.w = ls3 + T + rT;    // col 4t+3 : window 4t-1 .. 4t+7
        *reinterpret_cast<float4*>(op + (size_t)(h0 + j) * W) = o;
    }
}

extern "C" void kernel_launch(void* const* d_in, const int* in_sizes, int n_in,
                              void* d_out, int out_size, void* d_ws, size_t ws_size,
                              hipStream_t stream) {
    const float* x   = (const float*)d_in[0];
    float*       out = (float*)d_out;
    const int n_blocks = NIMG * NCHUNK;   // 24 * 64 = 1536, all productive
    box9_kernel<<<dim3(n_blocks), dim3(TPB), 0, stream>>>(x, out);
}

// Round 7
// 43.117 us; speedup vs baseline: 1.0249x; 1.0249x over previous
//
#include <hip/hip_runtime.h>

// 9x9 clipped box-SUM on (8,3,1024,1024) f32 — fused, zero-waste 4-strip
// layout, barrier-free.
//
// 4 strips x 256 cols = exactly W=1024: EVERY lane owns an output float4
// (round 4 wasted 20% of wave capacity on strip overhang). Loads/stores are
// perfect 1KB-aligned wave segments.
//
// Vertical: per-lane rolling 9-row window sum V over a 16-row chunk, staged
// r[25], all-static indices (rule #20; compiler sinks loads to a ~9-row live
// window — proven in round 4). Edge lanes (0 and 63) additionally maintain V2,
// the neighbor strip's boundary float4 vertical sum, via exec-masked loads
// (2 active lanes, ~3% extra bytes, L2/L3-hot).
//
// Horizontal: 9-tap via 8 in-wave shuffles; at wave edges the neighbor V is
// V2 (cndmask select). No LDS, no __syncthreads anywhere.
// Tripwire: WRITE_SIZE must stay ~96 MB (scratch spill shows up there).

constexpr int H = 1024, W = 1024;
constexpr int RAD = 4;
constexpr int CHUNK = 16;
constexpr int NCHUNK = H / CHUNK;            // 64
constexpr int NSTRIP = 4;                    // 4 x 256 cols = 1024, zero waste
constexpr int NIMG = 24;                     // 8 * 3
constexpr int NROWS = CHUNK + 2 * RAD + 1;   // 25
constexpr int HW = H * W;

__global__ __launch_bounds__(256) void box9_kernel(const float* __restrict__ x,
                                                   float* __restrict__ out) {
    const int lane = threadIdx.x & 63;
    const int wid  = blockIdx.x * 4 + (threadIdx.x >> 6);

    const int chunk = wid & (NCHUNK - 1);   // fastest-varying: adjacent chunks
    const int rest  = wid >> 6;             // share vertical-halo rows in L2
    const int strip = rest & (NSTRIP - 1);
    const int img   = rest >> 2;

    const int cs = strip * 256 + 4 * lane;  // own float4 col; always in-bounds
    const float* xp = x   + (size_t)img * HW + cs;
    float*       op = out + (size_t)img * HW + cs;

    // Edge lanes track the neighbor strip's boundary float4.
    const bool isL  = (lane == 0);
    const bool isR  = (lane == 63);
    const bool has2 = (isL && strip > 0) || (isR && strip < NSTRIP - 1);
    const int  cs2  = isL ? (cs - 4) : (cs + 4);
    const float* xp2 = x + (size_t)img * HW + (has2 ? cs2 : cs);

    const int h0 = chunk * CHUNK;

    // Stage chunk + vertical halo. r2 loads are exec-masked (2 lanes/wave).
    float4 r[NROWS], r2[NROWS];
#pragma unroll
    for (int j = 0; j < NROWS; ++j) {
        const int  row = h0 - RAD + j;
        const bool rok = (unsigned)row < (unsigned)H;
        r[j] = rok ? *reinterpret_cast<const float4*>(xp + (size_t)row * W)
                   : make_float4(0.f, 0.f, 0.f, 0.f);
        r2[j] = (rok && has2)
              ? *reinterpret_cast<const float4*>(xp2 + (size_t)row * W)
              : make_float4(0.f, 0.f, 0.f, 0.f);
    }

    // V / V2 = vertical 9-row window sums, init over rows h0-4 .. h0+4.
    float4 V  = make_float4(0.f, 0.f, 0.f, 0.f);
    float4 V2 = make_float4(0.f, 0.f, 0.f, 0.f);
#pragma unroll
    for (int j = 0; j < 9; ++j) {
        V.x  += r[j].x;  V.y  += r[j].y;  V.z  += r[j].z;  V.w  += r[j].w;
        V2.x += r2[j].x; V2.y += r2[j].y; V2.z += r2[j].z; V2.w += r2[j].w;
    }

#pragma unroll
    for (int j = 0; j < CHUNK; ++j) {
        // Neighbor V via 8 independent shuffles; wave-edge lanes use V2.
        float4 VL, VR;
        VL.x = __shfl(V.x, lane - 1);
        VL.y = __shfl(V.y, lane - 1);
        VL.z = __shfl(V.z, lane - 1);
        VL.w = __shfl(V.w, lane - 1);
        VR.x = __shfl(V.x, lane + 1);
        VR.y = __shfl(V.y, lane + 1);
        VR.z = __shfl(V.z, lane + 1);
        VR.w = __shfl(V.w, lane + 1);
        if (isL) VL = V2;   // strip 0: V2 == 0 == clipped image edge
        if (isR) VR = V2;   // strip 3: V2 == 0 == clipped image edge

        const float T   = V.x + V.y + V.z + V.w;
        const float ls3 = VL.w;
        const float ls2 = ls3 + VL.z;
        const float ls1 = ls2 + VL.y;
        const float lT  = ls1 + VL.x;
        const float rp0 = VR.x;
        const float rp1 = rp0 + VR.y;
        const float rp2 = rp1 + VR.z;
        const float rT  = rp2 + VR.w;

        float4 o;
        o.x = lT  + T + rp0;   // col cs   : window cs-4 .. cs+4
        o.y = ls1 + T + rp1;   // col cs+1
        o.z = ls2 + T + rp2;   // col cs+2
        o.w = ls3 + T + rT;    // col cs+3 : window cs-1 .. cs+7
        *reinterpret_cast<float4*>(op + (size_t)(h0 + j) * W) = o;

        // Roll vertical windows (static indices).
        V.x  += r[j + 9].x  - r[j].x;
        V.y  += r[j + 9].y  - r[j].y;
        V.z  += r[j + 9].z  - r[j].z;
        V.w  += r[j + 9].w  - r[j].w;
        V2.x += r2[j + 9].x - r2[j].x;
        V2.y += r2[j + 9].y - r2[j].y;
        V2.z += r2[j + 9].z - r2[j].z;
        V2.w += r2[j + 9].w - r2[j].w;
    }
}

extern "C" void kernel_launch(void* const* d_in, const int* in_sizes, int n_in,
                              void* d_out, int out_size, void* d_ws, size_t ws_size,
                              hipStream_t stream) {
    const float* x   = (const float*)d_in[0];
    float*       out = (float*)d_out;
    const int n_waves  = NIMG * NSTRIP * NCHUNK;   // 24*4*64 = 6144
    const int n_blocks = n_waves / 4;              // 1536 = exactly 6 per CU
    box9_kernel<<<dim3(n_blocks), dim3(256), 0, stream>>>(x, out);
}

// Round 8
// 39.344 us; speedup vs baseline: 1.1232x; 1.0959x over previous
//
#include <hip/hip_runtime.h>

// 9x9 clipped box-SUM on (8,3,1024,1024) f32 — round-4 structure, CHUNK=32.
//
// Wave = 64 lanes x 4 cols = 256 columns (248 outputs + 4-col halo/side).
// Each wave owns a 32-row chunk: stages all 41 needed rows (32 + 9 halo) as
// r[41] with fully-static indices; the compiler sinks loads to a ~10-row
// live window (proven in round 4: r[25] -> VGPR 72), so VGPRs stay moderate.
// CHUNK 16->32 cuts vertical-halo re-fetch from 1.56x to 1.28x of input and
// halves warm-up overhead per output row.
//
// Vertical: rolling 9-row window sum V (pure-register, static indices).
// Horizontal: out[k] = sfx_left[k] + T + pfx_right[k] via 8 independent
// shuffles, 2-deep add chain. No LDS, no barriers.
//
// Lessons encoded: no per-chunk register arrays beyond r[] (rounds 6/7:
// V16/r2 arrays -> wave-uniform VGPR blowup -> occupancy 19% -> regression).
// Tripwire: WRITE_SIZE must stay ~97 MB (scratch spill shows there).

constexpr int H = 1024, W = 1024;
constexpr int RAD = 4;
constexpr int OUTW = 248;               // (64 - 2 halo lanes) * 4 cols
constexpr int NSTRIP = 5;               // ceil(1024 / 248)
constexpr int CHUNK = 32;
constexpr int NCHUNK = H / CHUNK;       // 32
constexpr int NIMG = 24;                // 8 * 3
constexpr int NROWS = CHUNK + 2 * RAD + 1;  // 41

__global__ __launch_bounds__(256) void box9_kernel(const float* __restrict__ x,
                                                   float* __restrict__ out) {
    const int lane = threadIdx.x & 63;
    const int wid  = blockIdx.x * 4 + (threadIdx.x >> 6);

    const int chunk = wid & (NCHUNK - 1);       // adjacent chunks adjacent in
    const int t     = wid >> 5;                 // wid -> halo rows L1/L2-hot
    const int strip = t % NSTRIP;
    const int img   = t / NSTRIP;

    const int  cs  = strip * OUTW - RAD + lane * 4;   // first col this lane holds
    const bool cok = (cs >= 0) && (cs + 3 < W);       // float4 always 16B-aligned
    const float* xp = x   + (size_t)img * (H * W) + (cok ? cs : 0);
    float*       op = out + (size_t)img * (H * W) + (cok ? cs : 0);

    const int h0 = chunk * CHUNK;

    // Stage the whole chunk (+ vertical halo) in registers; the compiler
    // sinks these into the loop keeping ~10 rows live.
    float4 r[NROWS];
#pragma unroll
    for (int j = 0; j < NROWS; ++j) {
        const int row = h0 - RAD + j;
        r[j] = (cok && (unsigned)row < (unsigned)H)
             ? *reinterpret_cast<const float4*>(xp + (size_t)row * W)
             : make_float4(0.f, 0.f, 0.f, 0.f);
    }

    // V = vertical 9-row window sum, initialized over rows h0-4 .. h0+4.
    float4 V = make_float4(0.f, 0.f, 0.f, 0.f);
#pragma unroll
    for (int j = 0; j < 9; ++j) {
        V.x += r[j].x; V.y += r[j].y; V.z += r[j].z; V.w += r[j].w;
    }

    const bool sok = cok && (lane >= 1) && (lane <= 62);  // halo lanes don't store

#pragma unroll
    for (int j = 0; j < CHUNK; ++j) {
        // Own prefix/suffix sums of V (3-deep).
        const float p0 = V.x, p1 = p0 + V.y, p2 = p1 + V.z, T = p2 + V.w;
        const float s3 = V.w, s2 = s3 + V.z, s1 = s2 + V.y;
        // 8 INDEPENDENT shuffles: suffixes from left lane, prefixes from right.
        const float L0 = __shfl(T,  lane - 1);
        const float L1 = __shfl(s1, lane - 1);
        const float L2 = __shfl(s2, lane - 1);
        const float L3 = __shfl(s3, lane - 1);
        const float R0 = __shfl(p0, lane + 1);
        const float R1 = __shfl(p1, lane + 1);
        const float R2 = __shfl(p2, lane + 1);
        const float R3 = __shfl(T,  lane + 1);
        float4 o;
        o.x = L0 + T + R0;   // 9-wide horizontal windows for cols cs..cs+3
        o.y = L1 + T + R1;
        o.z = L2 + T + R2;
        o.w = L3 + T + R3;
        if (sok) *reinterpret_cast<float4*>(op + (size_t)(h0 + j) * W) = o;

        // Roll vertical window: add row h0+j+5, drop row h0+j-4 (static idx).
        V.x += r[j + 9].x - r[j].x;
        V.y += r[j + 9].y - r[j].y;
        V.z += r[j + 9].z - r[j].z;
        V.w += r[j + 9].w - r[j].w;
    }
}

extern "C" void kernel_launch(void* const* d_in, const int* in_sizes, int n_in,
                              void* d_out, int out_size, void* d_ws, size_t ws_size,
                              hipStream_t stream) {
    const float* x   = (const float*)d_in[0];
    float*       out = (float*)d_out;
    const int n_waves  = NIMG * NSTRIP * NCHUNK;   // 24*5*32 = 3840
    const int n_blocks = n_waves / 4;              // 960 blocks of 4 waves
    box9_kernel<<<dim3(n_blocks), dim3(256), 0, stream>>>(x, out);
}